// Round 2
// baseline (203.864 us; speedup 1.0000x reference)
//
#include <hip/hip_runtime.h>

#define BN_EPS 1e-3f

typedef __attribute__((ext_vector_type(8))) short bf16x8;
typedef __attribute__((ext_vector_type(4))) float f32x4;

__device__ inline unsigned short f2b(float f) {
    unsigned int u = __float_as_uint(f);
    unsigned int r = (u + 0x7fffu + ((u >> 16) & 1u)) >> 16;
    return (unsigned short)r;
}
__device__ inline float b2f(unsigned short h) {
    return __uint_as_float(((unsigned int)h) << 16);
}

// ---------------------------------------------------------------------------
// k_prep: Bt[n][k] = bf16 of (n<256 ? Wi[k][n] : Wr[k][n-256])   [320,256]
//         Wst[n][k] = bf16 of Ws[k][n]                            [144,64]
// ---------------------------------------------------------------------------
__global__ void k_prep(const float* __restrict__ Wi, const float* __restrict__ Wr,
                       const float* __restrict__ Ws,
                       unsigned short* __restrict__ Bt, unsigned short* __restrict__ Wst) {
    int t = blockIdx.x * 256 + threadIdx.x;
    if (t < 320 * 256) {
        int n = t >> 8, k = t & 255;
        float v = (n < 256) ? Wi[k * 256 + n] : Wr[k * 64 + (n - 256)];
        Bt[t] = f2b(v);
    } else {
        int t2 = t - 320 * 256;
        if (t2 < 144 * 64) {
            int n = t2 >> 6, k = t2 & 63;
            Wst[t2] = f2b(Ws[k * 144 + n]);
        }
    }
}

// ---------------------------------------------------------------------------
// k_fused: one block = one 8x8 output tile (halo 10x10 = 100 px).
// 512 threads, LDS 71,232 B -> TWO blocks/CU so one block's VALU-heavy
// gather (phase 3) overlaps the other's LDS/MFMA phase 1.
//   phase 1 (7 chunks of 16 halo rows, in-place LDS): wave wv owns xi
//       n-tiles {wv, wv+8}; waves 0-3 additionally own r n-tile 16+wv.
//   phase 2: w = r @ Wst^T (+bs); RS read to regs -> barrier -> WL
//       overwrites the (dead) RS region.
//   phase 3: contiguous-run gather; half-wave shares g (bank-friendly).
// LDS (u16): XI 100x264 | max(RS 100x72, WL 64x144)  = 71,232 B.
// ---------------------------------------------------------------------------
#define XIP 264
#define NHROW 100
#define RS_OFF (NHROW * XIP)          // 26400 u16
#define RSP 72
#define WL_OFF RS_OFF                 // WL aliases RS (RS dead after phase 2 reads)
#define SMN (RS_OFF + 64 * 144)       // 35616 u16 = 71,232 B

__global__ __launch_bounds__(512, 4) void k_fused(
    const float* __restrict__ x, const unsigned short* __restrict__ Bt,
    const unsigned short* __restrict__ Wst,
    const float* __restrict__ bi, const float* __restrict__ br,
    const float* __restrict__ gamma, const float* __restrict__ beta,
    const float* __restrict__ mean, const float* __restrict__ var,
    const float* __restrict__ bs, float* __restrict__ out)
{
    __shared__ __attribute__((aligned(16))) unsigned short sm[SMN];
    const int tid = threadIdx.x;
    const int bx = blockIdx.x;
    const int w0 = (bx & 15) * 8;
    const int h0 = ((bx >> 4) & 15) * 8;
    const int bb = bx >> 8;

    const int wv = tid >> 6;          // 0..7
    const int lane = tid & 63;
    const int col = lane & 15;
    const int quad = lane >> 4;

    // ---- per-wave constants & register-resident B fragments ----
    const float bi_v0 = bi[wv * 16 + col];
    const float bi_v1 = bi[(wv + 8) * 16 + col];
    const int dcl = (wv & 3) * 16 + col;       // r-column (valid when wv<4)
    const float r_sc = gamma[dcl] * rsqrtf(var[dcl] + BN_EPS);
    const float r_bias = (br[dcl] - mean[dcl]) * r_sc + beta[dcl];

    bf16x8 bx0[8], bx1[8], brr[8];
    {
        const unsigned short* p0 = &Bt[(wv * 16 + col) * 256];
        const unsigned short* p1 = &Bt[((wv + 8) * 16 + col) * 256];
#pragma unroll
        for (int kc = 0; kc < 8; ++kc) {
            bx0[kc] = *(const bf16x8*)&p0[kc * 32 + quad * 8];
            bx1[kc] = *(const bf16x8*)&p1[kc * 32 + quad * 8];
        }
        if (wv < 4) {
            const unsigned short* pr = &Bt[(256 + wv * 16 + col) * 256];
#pragma unroll
            for (int kc = 0; kc < 8; ++kc)
                brr[kc] = *(const bf16x8*)&pr[kc * 32 + quad * 8];
        }
    }

    // ---- staging: 32 threads/row, thread covers channels {chq..+3, chq+128..+131} ----
    const int chq = (tid & 31) * 4;
    const int hpt = tid >> 5;          // 0..15: row within chunk

    // prologue: stage chunk 0 (halo rows 0..15)
    {
        const int hp = hpt;
        const int hr = hp / 10, hc = hp - hr * 10;
        const int gh = h0 - 1 + hr, gw = w0 - 1 + hc;
        const bool ok = ((unsigned)gh < 128u) && ((unsigned)gw < 128u);
        float4 v0, v1;
        if (ok) {
            const float* src = x + (((long long)(bb * 128 + gh)) * 128 + gw) * 256 + chq;
            v0 = *(const float4*)&src[0];
            v1 = *(const float4*)&src[128];
        } else {
            v0 = (float4){0.f, 0.f, 0.f, 0.f};
            v1 = v0;
        }
        uint2 pk;
        pk.x = (unsigned)f2b(v0.x) | ((unsigned)f2b(v0.y) << 16);
        pk.y = (unsigned)f2b(v0.z) | ((unsigned)f2b(v0.w) << 16);
        *(uint2*)&sm[hp * XIP + chq] = pk;
        pk.x = (unsigned)f2b(v1.x) | ((unsigned)f2b(v1.y) << 16);
        pk.y = (unsigned)f2b(v1.z) | ((unsigned)f2b(v1.w) << 16);
        *(uint2*)&sm[hp * XIP + chq + 128] = pk;
    }
    __syncthreads();

    // ---- chunk loop: 7 chunks of 16 halo rows ----
    for (int c = 0; c < 7; ++c) {
        // issue global loads for chunk c+1 (overlap with MFMAs below)
        float4 vn0, vn1;
        int hp_n = 200;
        if (c < 6) {
            hp_n = (c + 1) * 16 + hpt;            // up to 111
            const int hr = hp_n / 10, hc = hp_n - hr * 10;
            const int gh = h0 - 1 + hr, gw = w0 - 1 + hc;
            const bool ok = (hp_n < NHROW) && ((unsigned)gh < 128u) && ((unsigned)gw < 128u);
            if (ok) {
                const float* src = x + (((long long)(bb * 128 + gh)) * 128 + gw) * 256 + chq;
                vn0 = *(const float4*)&src[0];
                vn1 = *(const float4*)&src[128];
            } else {
                vn0 = (float4){0.f, 0.f, 0.f, 0.f};
                vn1 = vn0;
            }
        }

        // MFMA chunk c: one A-read per kc feeds 2 (or 3) register B tiles
        f32x4 acc0 = {0.f, 0.f, 0.f, 0.f}, acc1 = acc0, ar = acc0;
        {
            const int rowA = (c * 16 + col) * XIP;
#pragma unroll
            for (int kc = 0; kc < 8; ++kc) {
                const int kb = kc * 32 + quad * 8;
                bf16x8 a0 = *(const bf16x8*)&sm[rowA + kb];
                acc0 = __builtin_amdgcn_mfma_f32_16x16x32_bf16(a0, bx0[kc], acc0, 0, 0, 0);
                acc1 = __builtin_amdgcn_mfma_f32_16x16x32_bf16(a0, bx1[kc], acc1, 0, 0, 0);
                if (wv < 4)
                    ar = __builtin_amdgcn_mfma_f32_16x16x32_bf16(a0, brr[kc], ar, 0, 0, 0);
            }
        }
        __syncthreads();   // all reads of rows_c done

        // write staged chunk c+1 (rows disjoint from rows_c)
        if (c < 6 && hp_n < NHROW) {
            uint2 pk;
            pk.x = (unsigned)f2b(vn0.x) | ((unsigned)f2b(vn0.y) << 16);
            pk.y = (unsigned)f2b(vn0.z) | ((unsigned)f2b(vn0.w) << 16);
            *(uint2*)&sm[hp_n * XIP + chq] = pk;
            pk.x = (unsigned)f2b(vn1.x) | ((unsigned)f2b(vn1.y) << 16);
            pk.y = (unsigned)f2b(vn1.z) | ((unsigned)f2b(vn1.w) << 16);
            *(uint2*)&sm[hp_n * XIP + chq + 128] = pk;
        }

        // epilogue chunk c: xi -> XI rows_c (in place), r -> RS rows_c
        {
            const int n0 = wv * 16 + col;
            const int rb = c * 16 + quad * 4;
#pragma unroll
            for (int rg = 0; rg < 4; ++rg) {
                const int r0 = rb + rg;
                if (r0 < NHROW) {
                    sm[r0 * XIP + n0] = f2b(acc0[rg] + bi_v0);
                    sm[r0 * XIP + n0 + 128] = f2b(acc1[rg] + bi_v1);
                }
            }
            if (wv < 4) {
#pragma unroll
                for (int rg = 0; rg < 4; ++rg) {
                    const int r0 = rb + rg;
                    if (r0 < NHROW) {
                        float v = ar[rg] * r_sc + r_bias;
                        sm[RS_OFF + r0 * RSP + dcl] = f2b(fmaxf(v, 0.f));
                    }
                }
            }
        }
        __syncthreads();
    }

    // ---- phase 2: w = r @ Wst^T (+bs); wave -> (m = wv&3, j-group = wv>>2) ----
    {
        const int m = wv & 3;
        const int jh = wv >> 2;
        const int jb = jh * 5;
        const int njt = 5 - jh;          // jh0: j=0..4, jh1: j=5..8
        // interior px p2 = m*16+col -> halo row ((p2>>3)+1)*10 + (p2&7) + 1
        const int p2 = m * 16 + col;
        const int arow = RS_OFF + (((p2 >> 3) + 1) * 10 + (p2 & 7) + 1) * RSP;
        bf16x8 ra0 = *(const bf16x8*)&sm[arow + quad * 8];
        bf16x8 ra1 = *(const bf16x8*)&sm[arow + 32 + quad * 8];
        __syncthreads();                 // RS reads done before WL overwrite

        f32x4 wacc[5];
#pragma unroll
        for (int jj = 0; jj < 5; ++jj) wacc[jj] = (f32x4){0.f, 0.f, 0.f, 0.f};
#pragma unroll
        for (int jj = 0; jj < 5; ++jj) {
            if (jj < njt) {
                const unsigned short* wp = &Wst[((jb + jj) * 16 + col) * 64];
                bf16x8 wb0 = *(const bf16x8*)&wp[quad * 8];
                bf16x8 wb1 = *(const bf16x8*)&wp[32 + quad * 8];
                wacc[jj] = __builtin_amdgcn_mfma_f32_16x16x32_bf16(ra0, wb0, wacc[jj], 0, 0, 0);
                wacc[jj] = __builtin_amdgcn_mfma_f32_16x16x32_bf16(ra1, wb1, wacc[jj], 0, 0, 0);
            }
        }
#pragma unroll
        for (int jj = 0; jj < 5; ++jj) {
            if (jj < njt) {
                const int n = (jb + jj) * 16 + col;
                const float bv = bs[n];
                const int prow = m * 16 + quad * 4;
#pragma unroll
                for (int rg = 0; rg < 4; ++rg)
                    sm[WL_OFF + (prow + rg) * 144 + n] = f2b(wacc[jj][rg] + bv);
            }
        }
    }
    __syncthreads();

    // ---- phase 3: gather; half-wave shares g so XI rows differ per lane ----
    {
        const int g = tid >> 5;                // 0..15
        const int pidx = tid & 31;

        const int idx0 = g * 144;
        const int kp0  = idx0 >> 8;
        const int c0   = idx0 & 255;           // multiple of 16
        int len1 = 256 - c0; if (len1 > 144) len1 = 144;
        const int kp1  = kp0 + 1;
        const int koff0 = (kp0 / 3) * 10 + (kp0 % 3);
        const int koff1 = (kp1 <= 8) ? ((kp1 / 3) * 10 + (kp1 % 3)) : 0;

#pragma unroll
        for (int jj = 0; jj < 2; ++jj) {
            const int p = pidx + 32 * jj;      // interior px 0..63
            const int phb = (p >> 3) * 10 + (p & 7);
            const int base0 = (phb + koff0) * XIP + c0;
            const int base1 = (phb + koff1) * XIP;

            float wf[9];
#pragma unroll
            for (int kk = 0; kk < 9; ++kk)
                wf[kk] = b2f(sm[WL_OFF + p * 144 + g * 9 + kk]);

            float res[16];
            {
                int4 xv[9];
#pragma unroll
                for (int i = 0; i < 9; ++i) {
                    const int e = i * 8;
                    const int addr = (e < len1) ? (base0 + e) : (base1 + (e - len1));
                    xv[i] = *(const int4*)&sm[addr];
                }
#pragma unroll
                for (int f2 = 0; f2 < 8; ++f2) {
                    float a = 0.f;
#pragma unroll
                    for (int kk = 0; kk < 9; ++kk) {
                        const int e = f2 * 9 + kk;
                        const int word = ((const int*)&xv[e >> 3])[(e >> 1) & 3];
                        const unsigned short u = (e & 1) ? (unsigned short)(((unsigned)word) >> 16)
                                                         : (unsigned short)(word & 0xffff);
                        a += wf[kk] * b2f(u);
                    }
                    res[f2] = a;
                }
            }
            {
                int4 xv[9];
#pragma unroll
                for (int i = 9; i < 18; ++i) {
                    const int e = i * 8;
                    const int addr = (e < len1) ? (base0 + e) : (base1 + (e - len1));
                    xv[i - 9] = *(const int4*)&sm[addr];
                }
#pragma unroll
                for (int f2 = 8; f2 < 16; ++f2) {
                    float a = 0.f;
#pragma unroll
                    for (int kk = 0; kk < 9; ++kk) {
                        const int e = f2 * 9 + kk;
                        const int i = (e >> 3) - 9;
                        const int word = ((const int*)&xv[i])[(e >> 1) & 3];
                        const unsigned short u = (e & 1) ? (unsigned short)(((unsigned)word) >> 16)
                                                         : (unsigned short)(word & 0xffff);
                        a += wf[kk] * b2f(u);
                    }
                    res[f2] = a;
                }
            }

            const long long orow =
                (((long long)(bb * 128 + h0 + (p >> 3))) * 128 + (w0 + (p & 7))) * 256 + g * 16;
#pragma unroll
            for (int q = 0; q < 4; ++q) {
                float4 o = {res[q * 4 + 0], res[q * 4 + 1], res[q * 4 + 2], res[q * 4 + 3]};
                *(float4*)&out[orow + q * 4] = o;
            }
        }
    }
}

// ---------------------------------------------------------------------------
extern "C" void kernel_launch(void* const* d_in, const int* in_sizes, int n_in,
                              void* d_out, int out_size, void* d_ws, size_t ws_size,
                              hipStream_t stream) {
    const float* x     = (const float*)d_in[0];
    const float* Wr    = (const float*)d_in[1];
    const float* br    = (const float*)d_in[2];
    const float* gamma = (const float*)d_in[3];
    const float* beta  = (const float*)d_in[4];
    const float* mean  = (const float*)d_in[5];
    const float* var   = (const float*)d_in[6];
    const float* Ws    = (const float*)d_in[7];
    const float* bs    = (const float*)d_in[8];
    const float* Wi    = (const float*)d_in[9];
    const float* bi    = (const float*)d_in[10];
    float* out = (float*)d_out;

    unsigned char* ws = (unsigned char*)d_ws;
    unsigned short* Bt  = (unsigned short*)(ws + 0);        // 320*256*2 = 163,840 B
    unsigned short* Wst = (unsigned short*)(ws + 163840);   // 144*64*2  =  18,432 B

    k_prep<<<dim3(356), dim3(256), 0, stream>>>(Wi, Wr, Ws, Bt, Wst);
    k_fused<<<dim3(1024), dim3(512), 0, stream>>>(
        x, Bt, Wst, bi, br, gamma, beta, mean, var, bs, out);
}

// Round 3
// 196.349 us; speedup vs baseline: 1.0383x; 1.0383x over previous
//
#include <hip/hip_runtime.h>

#define BN_EPS 1e-3f

typedef __attribute__((ext_vector_type(8))) short bf16x8;
typedef __attribute__((ext_vector_type(4))) float f32x4;

__device__ inline unsigned short f2b(float f) {
    unsigned int u = __float_as_uint(f);
    unsigned int r = (u + 0x7fffu + ((u >> 16) & 1u)) >> 16;
    return (unsigned short)r;
}
__device__ inline float b2f(unsigned short h) {
    return __uint_as_float(((unsigned int)h) << 16);
}

// ---------------------------------------------------------------------------
// k_prep: Bt[n][k] = bf16 of (n<256 ? Wi[k][n] : Wr[k][n-256])   [320,256]
//         Wst[n][k] = bf16 of Ws[k][n]                            [144,64]
// ---------------------------------------------------------------------------
__global__ void k_prep(const float* __restrict__ Wi, const float* __restrict__ Wr,
                       const float* __restrict__ Ws,
                       unsigned short* __restrict__ Bt, unsigned short* __restrict__ Wst) {
    int t = blockIdx.x * 256 + threadIdx.x;
    if (t < 320 * 256) {
        int n = t >> 8, k = t & 255;
        float v = (n < 256) ? Wi[k * 256 + n] : Wr[k * 64 + (n - 256)];
        Bt[t] = f2b(v);
    } else {
        int t2 = t - 320 * 256;
        if (t2 < 144 * 64) {
            int n = t2 >> 6, k = t2 & 63;
            Wst[t2] = f2b(Ws[k * 144 + n]);
        }
    }
}

// ---------------------------------------------------------------------------
// k_xiw: per block, 64 consecutive pixels (no halo).
//   xi[p][256] = bf16(x@Wi + bi)          -> xi_g
//   r = relu(BN(x@Wr)) (LDS only), w[p][144] = bf16(r@Ws^T + bs) -> w_g
// 256 threads (4 waves). Wave wv owns n-tiles j = wv*5..wv*5+4 of N=320
// (j<16: xi, j>=16: r), all 4 m-tiles. B streamed from L2-resident Bt.
// LDS (u16): X [64][264] | RS [64][72] = 43,008 B -> 3 blocks/CU.
// ---------------------------------------------------------------------------
#define AXIP 264
#define ARS_OFF (64 * AXIP)          // 16896 u16
#define ASMN (ARS_OFF + 64 * 72)     // 21504 u16 = 43,008 B

__global__ __launch_bounds__(256, 3) void k_xiw(
    const float* __restrict__ x, const unsigned short* __restrict__ Bt,
    const unsigned short* __restrict__ Wst,
    const float* __restrict__ bi, const float* __restrict__ br,
    const float* __restrict__ gamma, const float* __restrict__ beta,
    const float* __restrict__ mean, const float* __restrict__ var,
    const float* __restrict__ bs,
    unsigned short* __restrict__ xi_g, unsigned short* __restrict__ w_g)
{
    __shared__ __attribute__((aligned(16))) unsigned short sm[ASMN];
    const int tid = threadIdx.x;
    const long long px0 = (long long)blockIdx.x * 64;

    const int wv = tid >> 6;          // 0..3
    const int lane = tid & 63;
    const int col = lane & 15;
    const int quad = lane >> 4;

    // ---- stage x[64][256] f32 -> X LDS bf16 (fully coalesced) ----
#pragma unroll
    for (int it = 0; it < 8; ++it) {
        const int flat = it * 256 + tid;       // chunk of 8 floats
        const int px = flat >> 5;
        const int cho = (flat & 31) * 8;
        const float* src = x + (px0 + px) * 256 + cho;
        float4 v0 = *(const float4*)&src[0];
        float4 v1 = *(const float4*)&src[4];
        int4 pk;
        pk.x = (int)((unsigned)f2b(v0.x) | ((unsigned)f2b(v0.y) << 16));
        pk.y = (int)((unsigned)f2b(v0.z) | ((unsigned)f2b(v0.w) << 16));
        pk.z = (int)((unsigned)f2b(v1.x) | ((unsigned)f2b(v1.y) << 16));
        pk.w = (int)((unsigned)f2b(v1.z) | ((unsigned)f2b(v1.w) << 16));
        *(int4*)&sm[px * AXIP + cho] = pk;
    }
    __syncthreads();

    // ---- main GEMM: M=64 (4 m-tiles), N=320 (wave: 5 j-tiles), K=256 ----
    f32x4 acc[5][4];
#pragma unroll
    for (int jj = 0; jj < 5; ++jj)
#pragma unroll
        for (int m = 0; m < 4; ++m) acc[jj][m] = (f32x4){0.f, 0.f, 0.f, 0.f};

#pragma unroll
    for (int kc = 0; kc < 8; ++kc) {
        const int kb = kc * 32 + quad * 8;
        bf16x8 a[4];
#pragma unroll
        for (int m = 0; m < 4; ++m)
            a[m] = *(const bf16x8*)&sm[(m * 16 + col) * AXIP + kb];
#pragma unroll
        for (int jj = 0; jj < 5; ++jj) {
            const int j = wv * 5 + jj;
            bf16x8 b = *(const bf16x8*)&Bt[(j * 16 + col) * 256 + kb];
#pragma unroll
            for (int m = 0; m < 4; ++m)
                acc[jj][m] = __builtin_amdgcn_mfma_f32_16x16x32_bf16(a[m], b, acc[jj][m], 0, 0, 0);
        }
    }
    __syncthreads();   // all X reads done

    // ---- epilogue: xi tiles -> X region (overwrite), r tiles -> RS ----
#pragma unroll
    for (int jj = 0; jj < 5; ++jj) {
        const int j = wv * 5 + jj;
        if (j < 16) {
            const int n = j * 16 + col;
            const float bv = bi[n];
#pragma unroll
            for (int m = 0; m < 4; ++m)
#pragma unroll
                for (int rg = 0; rg < 4; ++rg) {
                    const int row = m * 16 + quad * 4 + rg;
                    sm[row * AXIP + n] = f2b(acc[jj][m][rg] + bv);
                }
        } else {
            const int d = (j - 16) * 16 + col;
            const float sc = gamma[d] * rsqrtf(var[d] + BN_EPS);
            const float bb2 = (br[d] - mean[d]) * sc + beta[d];
#pragma unroll
            for (int m = 0; m < 4; ++m)
#pragma unroll
                for (int rg = 0; rg < 4; ++rg) {
                    const int row = m * 16 + quad * 4 + rg;
                    const float v = acc[jj][m][rg] * sc + bb2;
                    sm[ARS_OFF + row * 72 + d] = f2b(fmaxf(v, 0.f));
                }
        }
    }
    __syncthreads();   // X now holds xi bf16; RS holds r bf16

    // ---- w-GEMM: wave wv -> m-tile wv; N=144 (9 j), K=64 ----
    f32x4 wa[9];
#pragma unroll
    for (int j = 0; j < 9; ++j) wa[j] = (f32x4){0.f, 0.f, 0.f, 0.f};
#pragma unroll
    for (int kc = 0; kc < 2; ++kc) {
        const int kb = kc * 32 + quad * 8;
        bf16x8 ra = *(const bf16x8*)&sm[ARS_OFF + (wv * 16 + col) * 72 + kb];
#pragma unroll
        for (int j = 0; j < 9; ++j) {
            bf16x8 wb = *(const bf16x8*)&Wst[(j * 16 + col) * 64 + kb];
            wa[j] = __builtin_amdgcn_mfma_f32_16x16x32_bf16(ra, wb, wa[j], 0, 0, 0);
        }
    }

    // ---- xi copy-out (coalesced 16B stores) ----
#pragma unroll
    for (int it = 0; it < 8; ++it) {
        const int flat = it * 256 + tid;
        const int px = flat >> 5;
        const int cho = (flat & 31) * 8;
        int4 v = *(const int4*)&sm[px * AXIP + cho];
        *(int4*)&xi_g[(px0 + px) * 256 + cho] = v;
    }

    // ---- w store (direct; rows merge to full lines in L2) ----
#pragma unroll
    for (int j = 0; j < 9; ++j) {
        const int n = j * 16 + col;
        const float bv = bs[n];
#pragma unroll
        for (int rg = 0; rg < 4; ++rg) {
            const int row = wv * 16 + quad * 4 + rg;
            w_g[(px0 + row) * 144 + n] = f2b(wa[j][rg] + bv);
        }
    }
}

// ---------------------------------------------------------------------------
// k_gather: one block = 8x8 output tile (halo 10x10 = 100 px).
// 512 threads (8 waves). Stage xi halo + w tile -> ONE barrier -> gather.
// LDS (u16): XI [100][264] | WL [64][144] = 71,232 B -> 2 blocks/CU.
// ---------------------------------------------------------------------------
#define GXIP 264
#define GWL_OFF (100 * GXIP)            // 26400 u16
#define GSMN (GWL_OFF + 64 * 144)       // 35616 u16 = 71,232 B

__global__ __launch_bounds__(512, 4) void k_gather(
    const unsigned short* __restrict__ xi_g, const unsigned short* __restrict__ w_g,
    float* __restrict__ out)
{
    __shared__ __attribute__((aligned(16))) unsigned short sm[GSMN];
    const int tid = threadIdx.x;
    // bijective XCD swizzle (1024 blocks, 1024 % 8 == 0)
    const int b = blockIdx.x;
    const int bx = (b & 7) * 128 + (b >> 3);
    const int w0 = (bx & 15) * 8;
    const int h0 = ((bx >> 4) & 15) * 8;
    const int bb = bx >> 8;

    // ---- stage XI halo: 100 px x 256 ch bf16 = 3200 chunks of 16B ----
#pragma unroll
    for (int it = 0; it < 7; ++it) {
        const int flat = it * 512 + tid;
        if (flat < 3200) {
            const int px = flat >> 5;
            const int cho = (flat & 31) * 8;
            const int hr = px / 10, hc = px - hr * 10;
            const int gh = h0 - 1 + hr, gw = w0 - 1 + hc;
            int4 v;
            if (((unsigned)gh < 128u) && ((unsigned)gw < 128u)) {
                const long long pxg = ((long long)(bb * 128 + gh)) * 128 + gw;
                v = *(const int4*)&xi_g[pxg * 256 + cho];
            } else {
                v = (int4){0, 0, 0, 0};
            }
            *(int4*)&sm[px * GXIP + cho] = v;
        }
    }
    // ---- stage WL: 64 px x 144 = 1152 chunks of 16B ----
#pragma unroll
    for (int it = 0; it < 3; ++it) {
        const int flat = it * 512 + tid;
        if (flat < 1152) {
            const int px = flat / 18;
            const int cho = (flat - px * 18) * 8;
            const long long pxg =
                ((long long)(bb * 128 + h0 + (px >> 3))) * 128 + (w0 + (px & 7));
            int4 v = *(const int4*)&w_g[pxg * 144 + cho];
            *(int4*)&sm[GWL_OFF + px * 144 + cho] = v;
        }
    }
    __syncthreads();

    // ---- gather: g = tid&15 (coalesced 1KB out per 16-lane group) ----
    {
        const int g = tid & 15;
        const int pb = tid >> 4;               // 0..31

        const int idx0 = g * 144;
        const int kp0  = idx0 >> 8;
        const int c0   = idx0 & 255;           // multiple of 16
        int len1 = 256 - c0; if (len1 > 144) len1 = 144;
        const int kp1  = kp0 + 1;
        const int koff0 = (kp0 / 3) * 10 + (kp0 % 3);
        const int koff1 = (kp1 <= 8) ? ((kp1 / 3) * 10 + (kp1 % 3)) : 0;

#pragma unroll
        for (int jj = 0; jj < 2; ++jj) {
            const int p = pb + 32 * jj;        // interior px 0..63
            const int phb = (p >> 3) * 10 + (p & 7);
            const int base0 = (phb + koff0) * GXIP + c0;
            const int base1 = (phb + koff1) * GXIP;

            float wf[9];
#pragma unroll
            for (int kk = 0; kk < 9; ++kk)
                wf[kk] = b2f(sm[GWL_OFF + p * 144 + g * 9 + kk]);

            float res[16];
            {
                int4 xv[9];
#pragma unroll
                for (int i = 0; i < 9; ++i) {
                    const int e = i * 8;
                    const int addr = (e < len1) ? (base0 + e) : (base1 + (e - len1));
                    xv[i] = *(const int4*)&sm[addr];
                }
#pragma unroll
                for (int f2 = 0; f2 < 8; ++f2) {
                    float a = 0.f;
#pragma unroll
                    for (int kk = 0; kk < 9; ++kk) {
                        const int e = f2 * 9 + kk;
                        const int word = ((const int*)&xv[e >> 3])[(e >> 1) & 3];
                        const unsigned short u = (e & 1) ? (unsigned short)(((unsigned)word) >> 16)
                                                         : (unsigned short)(word & 0xffff);
                        a += wf[kk] * b2f(u);
                    }
                    res[f2] = a;
                }
            }
            {
                int4 xv[9];
#pragma unroll
                for (int i = 9; i < 18; ++i) {
                    const int e = i * 8;
                    const int addr = (e < len1) ? (base0 + e) : (base1 + (e - len1));
                    xv[i - 9] = *(const int4*)&sm[addr];
                }
#pragma unroll
                for (int f2 = 8; f2 < 16; ++f2) {
                    float a = 0.f;
#pragma unroll
                    for (int kk = 0; kk < 9; ++kk) {
                        const int e = f2 * 9 + kk;
                        const int i = (e >> 3) - 9;
                        const int word = ((const int*)&xv[i])[(e >> 1) & 3];
                        const unsigned short u = (e & 1) ? (unsigned short)(((unsigned)word) >> 16)
                                                         : (unsigned short)(word & 0xffff);
                        a += wf[kk] * b2f(u);
                    }
                    res[f2] = a;
                }
            }

            const long long orow =
                (((long long)(bb * 128 + h0 + (p >> 3))) * 128 + (w0 + (p & 7))) * 256 + g * 16;
#pragma unroll
            for (int q = 0; q < 4; ++q) {
                float4 o = {res[q * 4 + 0], res[q * 4 + 1], res[q * 4 + 2], res[q * 4 + 3]};
                *(float4*)&out[orow + q * 4] = o;
            }
        }
    }
}

// ---------------------------------------------------------------------------
extern "C" void kernel_launch(void* const* d_in, const int* in_sizes, int n_in,
                              void* d_out, int out_size, void* d_ws, size_t ws_size,
                              hipStream_t stream) {
    const float* x     = (const float*)d_in[0];
    const float* Wr    = (const float*)d_in[1];
    const float* br    = (const float*)d_in[2];
    const float* gamma = (const float*)d_in[3];
    const float* beta  = (const float*)d_in[4];
    const float* mean  = (const float*)d_in[5];
    const float* var   = (const float*)d_in[6];
    const float* Ws    = (const float*)d_in[7];
    const float* bs    = (const float*)d_in[8];
    const float* Wi    = (const float*)d_in[9];
    const float* bi    = (const float*)d_in[10];
    float* out = (float*)d_out;

    unsigned char* ws = (unsigned char*)d_ws;
    unsigned short* Bt   = (unsigned short*)(ws + 0);         // 163,840 B
    unsigned short* Wst  = (unsigned short*)(ws + 163840);    //  18,432 B
    unsigned short* xi_g = (unsigned short*)(ws + 182272);    // 65536*256*2 = 33,554,432 B
    unsigned short* w_g  = (unsigned short*)(ws + 33736704);  // 65536*144*2 = 18,874,368 B
    // total workspace use: 52,611,072 B

    k_prep<<<dim3(356), dim3(256), 0, stream>>>(Wi, Wr, Ws, Bt, Wst);
    k_xiw<<<dim3(1024), dim3(256), 0, stream>>>(
        x, Bt, Wst, bi, br, gamma, beta, mean, var, bs, xi_g, w_g);
    k_gather<<<dim3(1024), dim3(512), 0, stream>>>(xi_g, w_g, out);
}